// Round 10
// baseline (9002.474 us; speedup 1.0000x reference)
//
#include <hip/hip_runtime.h>

#define BDIM 128
#define TDIM 1024
#define HDIM 256
#define SLOT (BDIM*HDIM)
#define NWG_TOTAL 208             // 192 worker (3 layer x 4 rowgroup x 16 colslice) + 16 head
#define RING 14                   // h-plane ring depth per layer

// ws byte offsets. Flags: 16 groups x 16 x 32B = 8192 B.
#define FLAGS_OFF 0u              // u32 flag at idx (g*16+w)*8; g = l*4+rg (worker), 12+rg (head)
#define HD_OFF    8192u           // bf16 h digit planes [(l*RING+slot)*2+dig][B*H] = 5,505,024 B
#define XF_OFF    5513216u        // fp32 x features [B][T][6] = 3,145,728 B
#define DONEF_OFF 8658944u        // fp32 done [B][T] = 524,288 B
#define WS_NEEDED 9183232u        // <= proven 9,245,840
#define NZERO_U32 1378304         // (8192 + 5505024)/4

// dynamic LDS: worker = Wh frags [0,61440) + Wx frags [61440,122880); head 8KB
#define LDSW_BYTES 61440
#define LDS_DYN    122880

typedef __attribute__((ext_vector_type(8))) short bf16x8;
typedef __attribute__((ext_vector_type(4))) float f32x4;

static __device__ __forceinline__ unsigned short f2bf(float f) {
  union { float f; unsigned u; } v; v.f = f;
  unsigned r = v.u + 0x7fffu + ((v.u >> 16) & 1u);   // RNE
  return (unsigned short)(r >> 16);
}
static __device__ __forceinline__ float bf2f(unsigned short h) {
  union { unsigned u; float f; } v; v.u = ((unsigned)h) << 16;
  return v.f;
}
static __device__ __forceinline__ float sigm(float x) { return 1.f / (1.f + __expf(-x)); }
static __device__ __forceinline__ float tanha(float x) { return 1.f - 2.f / (1.f + __expf(2.f * x)); }

// data-plane coherence: relaxed agent atomics (LLC-routed) — R12-proven
static __device__ __forceinline__ unsigned long long ld_u64_coh(const void* p) {
  return __hip_atomic_load((const unsigned long long*)p, __ATOMIC_RELAXED, __HIP_MEMORY_SCOPE_AGENT);
}
static __device__ __forceinline__ void st_u32_coh(void* p, unsigned v) {
  __hip_atomic_store((unsigned*)p, v, __ATOMIC_RELAXED, __HIP_MEMORY_SCOPE_AGENT);
}

// R21: coherent 16B load, NO wait — issued in a batch; validity deferred to a
// counted s_waitcnt vmcnt(N) + sched_barrier(0) (rule #18). sc0 sc1 = bypass
// L1 + per-XCD L2 (same coherence point the u64 atomic path used).
static __device__ __forceinline__ bf16x8 ld16_coh_nowait(const unsigned short* p) {
  bf16x8 v;
  asm volatile("global_load_dwordx4 %0, %1, off sc0 sc1" : "=v"(v) : "v"(p));
  return v;
}
template <int N>
static __device__ __forceinline__ void wait_vm() {
  asm volatile("s_waitcnt vmcnt(%0)" :: "i"(N) : "memory");
  __builtin_amdgcn_sched_barrier(0);
}

static __device__ __forceinline__ unsigned poll_flag(const unsigned* p) {
  return __hip_atomic_load(p, __ATOMIC_RELAXED, __HIP_MEMORY_SCOPE_AGENT);
}
static __device__ __forceinline__ void post_flag(unsigned* fl, int g, int w, int s1) {
  (void)__hip_atomic_exchange(fl + (g * 16 + w) * 8, (unsigned)s1,
                              __ATOMIC_RELAXED, __HIP_MEMORY_SCOPE_AGENT);
}

// per-wave dataflow wait: lanes 0-15 group g0 (skip own w=skip0),
// lanes 16-31 g1, lanes 32-47 g2 (g2four: only 4 flags, lane&3), 48-63 idle.
static __device__ __forceinline__ void wave_wait2(unsigned* fl,
                                                  int g0, int t0, int skip0,
                                                  int g1, int t1,
                                                  int g2, int t2, bool g2four) {
  const int lane = threadIdx.x & 63;
  const int sel = lane >> 4;
  const int w = lane & 15;
  int g = g0, tgt = t0;
  if (sel == 1) { g = g1; tgt = t1; }
  if (sel == 2) { g = g2; tgt = t2; }
  if (sel == 3) tgt = 0;
  if (sel == 0 && w == skip0) tgt = 0;
  const int wi = (sel == 2 && g2four) ? (w & 3) : w;
  const unsigned* p = fl + (g * 16 + wi) * 8;
  const bool need = tgt > 0;
  for (;;) {
    int ok = 1;
    if (need) ok = ((int)poll_flag(p) >= tgt);
    if (__all(ok)) break;
    __builtin_amdgcn_s_sleep(8);
  }
  asm volatile("" ::: "memory");
}

__global__ void diag_kernel(float* out, float code) {
  if (threadIdx.x == 0 && blockIdx.x == 0) out[0] = code;
}

// ---------- prep: zero flags + h planes, build x-features, mirror done ----------
__global__ void prep_kernel(const float* __restrict__ rew, const float* __restrict__ done,
                            const float* __restrict__ gamma, const float* __restrict__ prob,
                            const float* __restrict__ y, const float* __restrict__ y1,
                            const float* __restrict__ w_e1, const float* __restrict__ b_e1,
                            const float* __restrict__ w_e2, const float* __restrict__ b_e2,
                            char* __restrict__ ws) {
  unsigned* zbase = (unsigned*)ws;
  float* donef = (float*)(ws + DONEF_OFF);
  float* xfeat = (float*)(ws + XF_OFF);

  __shared__ float we1[480], be1[16], we2[16];
  __shared__ float be2s, gam;
  for (int i = threadIdx.x; i < 480; i += blockDim.x) we1[i] = w_e1[i];
  if (threadIdx.x < 16) { be1[threadIdx.x] = b_e1[threadIdx.x]; we2[threadIdx.x] = w_e2[threadIdx.x]; }
  if (threadIdx.x == 0) { be2s = b_e2[0]; gam = gamma[0]; }
  __syncthreads();
  const int gid = blockIdx.x * blockDim.x + threadIdx.x;
  const int stride = gridDim.x * blockDim.x;

  for (int i = gid; i < NZERO_U32; i += stride) zbase[i] = 0u;
  for (int i = gid; i < BDIM * TDIM; i += stride) donef[i] = done[i];

  for (int i = gid; i < BDIM * TDIM; i += stride) {   // i = b*T + t
    float yr[30], y1r[30];
    #pragma unroll
    for (int c = 0; c < 30; ++c) { yr[c] = y[(size_t)i * 30 + c]; y1r[c] = y1[(size_t)i * 30 + c]; }
    float a0 = 0.f, a1 = 0.f;
    #pragma unroll 4
    for (int jm = 0; jm < 16; ++jm) {
      float s0 = be1[jm], s1 = be1[jm];
      #pragma unroll
      for (int c = 0; c < 30; ++c) { float w = we1[jm * 30 + c]; s0 += yr[c] * w; s1 += y1r[c] * w; }
      a0 += fmaxf(s0, 0.f) * we2[jm];
      a1 += fmaxf(s1, 0.f) * we2[jm];
    }
    float* xr = xfeat + (size_t)i * 6;
    xr[0] = rew[i]; xr[1] = done[i]; xr[2] = gam;
    xr[3] = prob[i]; xr[4] = sigm(a0 + be2s); xr[5] = sigm(a1 + be2s);
  }
}

// ---------------- worker WG: 2 waves, LDS weights, batch-issued wide loads -------
// Wave wv owns rows (rg*2+wv)*16..+15. Weights (Wh AND Wx) live in LDS in the
// R18-proven fragment layout (bit-identical operand values to the VGPR path);
// this frees ~190 VGPRs so ALL 32 fragment loads issue nowait and fly together
// (one HBM RTT instead of ~16 serialized batches).
// flag groups: worker g = l*4+rg (w = js), head g = 12+rg (w = hw&3).
template <bool L0T>
__device__ __forceinline__ void layer_body(int l, int rg, int js, char* __restrict__ ws,
                                           char* __restrict__ ldsW,
                                           char* __restrict__ ldsX,
                                           const float* __restrict__ Wh,
                                           const float* __restrict__ Wx,
                                           const float* __restrict__ bi,
                                           const float* __restrict__ bh,
                                           const float* __restrict__ wi0) {
  unsigned short* hd = (unsigned short*)(ws + HD_OFF);
  unsigned* fl = (unsigned*)(ws + FLAGS_OFF);
  const float* donef = (const float*)(ws + DONEF_OFF);
  const float* xfeat = (const float*)(ws + XF_OFF);

  const int tid = threadIdx.x;
  const int wv = tid >> 6, lane = tid & 63, q = lane >> 4, jj = lane & 15;
  const int j = js * 16 + jj;

  const float bi_r = bi[j], bi_z = bi[256 + j], bi_n = bi[512 + j];
  const float bh_r = bh[j], bh_z = bh[256 + j], bh_n = bh[512 + j];

  // stage Wh digit frags -> LDS (128 threads; same values/layout as VGPR Bh)
  for (int idx = tid; idx < 12288; idx += 128) {
    const int row = idx >> 8, k = idx & 255;
    const int g = row >> 4, jr = row & 15;
    const float w = Wh[(size_t)(g * 256 + js * 16 + jr) * 256 + k];
    const unsigned short d1 = f2bf(w);
    const unsigned short d2 = f2bf(w - bf2f(d1));
    const int itc = k >> 5, kk = k & 31;
    *(unsigned short*)(ldsW + ((g * 2 + 0) * 8 + itc) * 1280 + jr * 80 + kk * 2) = d1;
    *(unsigned short*)(ldsW + ((g * 2 + 1) * 8 + itc) * 1280 + jr * 80 + kk * 2) = d2;
  }
  if (!L0T) {
    for (int idx = tid; idx < 12288; idx += 128) {
      const int row = idx >> 8, k = idx & 255;
      const int g = row >> 4, jr = row & 15;
      const float w = Wx[(size_t)(g * 256 + js * 16 + jr) * 256 + k];
      const unsigned short d1 = f2bf(w);
      const unsigned short d2 = f2bf(w - bf2f(d1));
      const int itc = k >> 5, kk = k & 31;
      *(unsigned short*)(ldsX + ((g * 2 + 0) * 8 + itc) * 1280 + jr * 80 + kk * 2) = d1;
      *(unsigned short*)(ldsX + ((g * 2 + 1) * 8 + itc) * 1280 + jr * 80 + kk * 2) = d2;
    }
  }
  __syncthreads();

  float wx0[3][6];
  if (L0T) {
    #pragma unroll
    for (int g = 0; g < 3; ++g)
      #pragma unroll
      for (int c = 0; c < 6; ++c) wx0[g][c] = wi0[(g * 256 + j) * 6 + c];
  }

  float hc[4];                     // fp32 carry: this wave's 16 rows x 16 cols
  #pragma unroll
  for (int i = 0; i < 4; ++i) hc[i] = 0.f;

  const int mA = (rg * 2 + wv) * 16 + jj;   // this wave's A-row base
  const f32x4 z4 = {0.f, 0.f, 0.f, 0.f};

  for (int s = 0; s < 1024; ++s) {
    const int t = 1023 - s;
    const int pc = s % RING, pp = (s + RING - 1) % RING;

    // prefetch done factors before the wait (drained during the poll loop)
    float sFv[4];
    #pragma unroll
    for (int i = 0; i < 4; ++i)
      sFv[i] = 1.f - donef[((rg * 2 + wv) * 16 + q * 4 + i) * TDIM + t];

    // dataflow waits (per rowgroup-pipeline) — both waves independently
    if (L0T)         wave_wait2(fl, rg,     s, js, 4 + rg,  s - (RING - 1), 0, 0, false);
    else if (l == 1) wave_wait2(fl, 4 + rg, s, js, rg,      s + 1, 8 + rg,  s - (RING - 1), false);
    else             wave_wait2(fl, 8 + rg, s, js, 4 + rg,  s + 1, 12 + rg, s - (RING - 1), true);

    const unsigned short* hh1 = hd + (size_t)((l * RING + pp) * 2 + 0) * SLOT;
    const unsigned short* hh2 = hd + (size_t)((l * RING + pp) * 2 + 1) * SLOT;
    const unsigned short* hx1 = L0T ? (const unsigned short*)0 : hd + (size_t)(((l - 1) * RING + pc) * 2 + 0) * SLOT;
    const unsigned short* hx2 = L0T ? (const unsigned short*)0 : hd + (size_t)(((l - 1) * RING + pc) * 2 + 1) * SLOT;
    unsigned short* hdw1 = hd + (size_t)((l * RING + pc) * 2 + 0) * SLOT;
    unsigned short* hdw2 = hd + (size_t)((l * RING + pc) * 2 + 1) * SLOT;

    // ---- batch-issue ALL fragment loads (hh first, then hx) ----
    bf16x8 A1[8], A2[8], X1[8], X2[8];
    #pragma unroll
    for (int it = 0; it < 8; ++it) {
      const size_t ro = (size_t)mA * 256 + it * 32 + q * 8;
      A1[it] = ld16_coh_nowait(hh1 + ro);
      A2[it] = ld16_coh_nowait(hh2 + ro);
    }
    if (!L0T) {
      #pragma unroll
      for (int it = 0; it < 8; ++it) {
        const size_t ro = (size_t)mA * 256 + it * 32 + q * 8;
        X1[it] = ld16_coh_nowait(hx1 + ro);
        X2[it] = ld16_coh_nowait(hx2 + ro);
      }
    }

    f32x4 Ch[3], Cx[3];
    #pragma unroll
    for (int g = 0; g < 3; ++g) { Ch[g] = z4; Cx[g] = z4; }

    // hh half ready (16 younger hx still in flight for l>0)
    if (L0T) wait_vm<0>(); else wait_vm<16>();
    #pragma unroll
    for (int it = 0; it < 8; ++it) {
      const int cb = it * 1280 + jj * 80 + q * 16;
      #pragma unroll
      for (int g = 0; g < 3; ++g) {
        #pragma unroll
        for (int dig = 0; dig < 2; ++dig) {
          const bf16x8 wb = *(const bf16x8*)(ldsW + ((g * 2 + dig) * 8) * 1280 + cb);
          Ch[g] = __builtin_amdgcn_mfma_f32_16x16x32_bf16(A1[it], wb, Ch[g], 0, 0, 0);
          Ch[g] = __builtin_amdgcn_mfma_f32_16x16x32_bf16(A2[it], wb, Ch[g], 0, 0, 0);
        }
      }
    }
    if (!L0T) {
      wait_vm<0>();
      #pragma unroll
      for (int it = 0; it < 8; ++it) {
        const int cb = it * 1280 + jj * 80 + q * 16;
        #pragma unroll
        for (int g = 0; g < 3; ++g) {
          #pragma unroll
          for (int dig = 0; dig < 2; ++dig) {
            const bf16x8 xb = *(const bf16x8*)(ldsX + ((g * 2 + dig) * 8) * 1280 + cb);
            Cx[g] = __builtin_amdgcn_mfma_f32_16x16x32_bf16(X1[it], xb, Cx[g], 0, 0, 0);
            Cx[g] = __builtin_amdgcn_mfma_f32_16x16x32_bf16(X2[it], xb, Cx[g], 0, 0, 0);
          }
        }
      }
    }

    // epilogue (verified; C/D layout row=q*4+i, col=jj)
    #pragma unroll
    for (int i = 0; i < 4; ++i) {
      const int mC = (rg * 2 + wv) * 16 + q * 4 + i;
      const float sF = sFv[i];
      float gxr, gxz, gxn;
      if (L0T) {
        const float* xr = xfeat + ((size_t)mC * TDIM + t) * 6;
        gxr = 0.f; gxz = 0.f; gxn = 0.f;
        #pragma unroll
        for (int c = 0; c < 6; ++c) {
          const float xv = xr[c];
          gxr += xv * wx0[0][c]; gxz += xv * wx0[1][c]; gxn += xv * wx0[2][c];
        }
      } else {
        gxr = Cx[0][i]; gxz = Cx[1][i]; gxn = Cx[2][i];
      }
      const float r = sigm(gxr + bi_r + sF * Ch[0][i] + bh_r);
      const float z = sigm(gxz + bi_z + sF * Ch[1][i] + bh_z);
      const float n = tanha(gxn + bi_n + r * (sF * Ch[2][i] + bh_n));
      const float hp = hc[i] * sF;
      const float hv = (1.f - z) * n + z * hp;
      hc[i] = hv;
      // lane-pair pack: even jj stores d1-plane u32 pair, odd jj d2-plane
      const unsigned short d1 = f2bf(hv);
      const unsigned short d2 = f2bf(hv - bf2f(d1));
      const int o1 = __shfl_xor((int)d1, 1, 64);
      const int o2 = __shfl_xor((int)d2, 1, 64);
      const unsigned val = (jj & 1) ? ((unsigned)(o2 & 0xffff) | ((unsigned)d2 << 16))
                                    : ((unsigned)d1 | ((unsigned)(o1 & 0xffff) << 16));
      unsigned short* bp = ((jj & 1) ? hdw2 : hdw1) + (size_t)mC * 256 + (j & ~1);
      st_u32_coh(bp, val);
    }

    // drain this wave's stores, join sibling wave, then flag post (RMW)
    asm volatile("s_waitcnt vmcnt(0)" ::: "memory");
    __syncthreads();
    if (tid == 0) post_flag(fl, l * 4 + rg, js, s + 1);
  }
}

// ---------------- head WG (128 threads, 8 batch rows) ----------------
__device__ __forceinline__ void head_body(int hw, char* __restrict__ ws, float* __restrict__ out,
                                          char* __restrict__ lds,
                                          const float* __restrict__ wfy,
                                          const float* __restrict__ bfy,
                                          const float* __restrict__ wfp,
                                          const float* __restrict__ bfp) {
  const unsigned short* hd = (const unsigned short*)(ws + HD_OFF);
  unsigned* fl = (unsigned*)(ws + FLAGS_OFF);
  float* hlds = (float*)lds;        // 8 rows x 256 f32 = 8KB

  const int tid = threadIdx.x;
  const int rg = hw >> 2;

  for (int s = 0; s < 1024; ++s) {
    const int t = 1023 - s;
    const int pc = s % RING;
    wave_wait2(fl, 8 + rg, s + 1, -1, 0, 0, 0, 0, false);

    // stage 8 rows: reconstruct h = d1 + d2 into LDS (2 x 128-lane passes)
    #pragma unroll
    for (int sub = 0; sub < 2; ++sub) {
      const int te = tid + 128 * sub;
      const size_t rowoff = (size_t)(hw * 8 + (te >> 5)) * 256 + (te & 31) * 8;
      const unsigned short* p1 = hd + (size_t)((2 * RING + pc) * 2 + 0) * SLOT + rowoff;
      const unsigned short* p2 = hd + (size_t)((2 * RING + pc) * 2 + 1) * SLOT + rowoff;
      unsigned long long q10 = ld_u64_coh(p1);
      unsigned long long q11 = ld_u64_coh(p1 + 4);
      unsigned long long q20 = ld_u64_coh(p2);
      unsigned long long q21 = ld_u64_coh(p2 + 4);
      float* dst = hlds + (te >> 5) * 256 + (te & 31) * 8;
      #pragma unroll
      for (int e = 0; e < 4; ++e) {
        dst[e]     = bf2f((unsigned short)(q10 >> (16 * e))) + bf2f((unsigned short)(q20 >> (16 * e)));
        dst[4 + e] = bf2f((unsigned short)(q11 >> (16 * e))) + bf2f((unsigned short)(q21 >> (16 * e)));
      }
    }
    __syncthreads();
    #pragma unroll
    for (int sub = 0; sub < 2; ++sub) {
      const int te = tid + 128 * sub;
      const int d = te & 31;
      const int bb = te >> 5;
      const int b = hw * 8 + bb;
      if (d < 31) {
        const float* wrow = (d < 30) ? (wfy + d * 256) : wfp;
        const float biasv = (d < 30) ? bfy[d] : bfp[0];
        const float* hr = hlds + bb * 256;
        float a0 = 0.f, a1 = 0.f;
        #pragma unroll 8
        for (int kk = 0; kk < 256; kk += 8) {
          const f32x4 h0 = *(const f32x4*)(hr + kk);
          const f32x4 h1 = *(const f32x4*)(hr + kk + 4);
          const f32x4 w0 = *(const f32x4*)(wrow + kk);
          const f32x4 w1 = *(const f32x4*)(wrow + kk + 4);
          a0 += h0[0]*w0[0] + h0[1]*w0[1] + h0[2]*w0[2] + h0[3]*w0[3];
          a1 += h1[0]*w1[0] + h1[1]*w1[1] + h1[2]*w1[2] + h1[3]*w1[3];
        }
        const float acc = a0 + a1;
        if (d < 30) out[BDIM * TDIM + ((size_t)b * TDIM + t) * 30 + d] = sigm(acc + biasv);
        else        out[(size_t)b * TDIM + t] = acc + biasv;
      }
    }
    __syncthreads();
    if (tid == 0) post_flag(fl, 12 + rg, hw & 3, s + 1);
  }
}

__global__ void __launch_bounds__(128, 1) gru_main(char* __restrict__ ws,
                                                   float* __restrict__ out,
                                                   const float* __restrict__ wi0,
                                                   const float* __restrict__ wh0,
                                                   const float* __restrict__ bi0,
                                                   const float* __restrict__ bh0,
                                                   const float* __restrict__ wi1,
                                                   const float* __restrict__ wh1,
                                                   const float* __restrict__ bi1,
                                                   const float* __restrict__ bh1,
                                                   const float* __restrict__ wi2,
                                                   const float* __restrict__ wh2,
                                                   const float* __restrict__ bi2,
                                                   const float* __restrict__ bh2,
                                                   const float* __restrict__ wfy,
                                                   const float* __restrict__ bfy,
                                                   const float* __restrict__ wfp,
                                                   const float* __restrict__ bfp) {
  extern __shared__ char lds[];
  const int bid = blockIdx.x;
  if (bid < 192) {
    const int l = bid >> 6;
    const int rg = (bid >> 4) & 3;
    const int js = bid & 15;
    const float* Wh = (l == 0) ? wh0 : (l == 1) ? wh1 : wh2;
    const float* Wx = (l == 0) ? (const float*)0 : (l == 1) ? wi1 : wi2;
    const float* bi = (l == 0) ? bi0 : (l == 1) ? bi1 : bi2;
    const float* bh = (l == 0) ? bh0 : (l == 1) ? bh1 : bh2;
    if (l == 0) layer_body<true>(l, rg, js, ws, lds, lds + LDSW_BYTES, Wh, Wx, bi, bh, wi0);
    else        layer_body<false>(l, rg, js, ws, lds, lds + LDSW_BYTES, Wh, Wx, bi, bh, wi0);
  } else {
    head_body(bid - 192, ws, out, lds, wfy, bfy, wfp, bfp);
  }
}

extern "C" void kernel_launch(void* const* d_in, const int* in_sizes, int n_in,
                              void* d_out, int out_size, void* d_ws, size_t ws_size,
                              hipStream_t stream) {
  static const int EXP_SIZES[26] = {131072, 131072, 1, 131072, 3932160, 3932160,
                                    4608, 196608, 768, 768,
                                    196608, 196608, 768, 768,
                                    196608, 196608, 768, 768,
                                    7680, 30, 256, 1, 480, 16, 16, 1};
  float code = 0.f;
  if (n_in != 26) code = 900.f;
  if (code == 0.f) {
    for (int i = 0; i < 26; ++i)
      if (in_sizes[i] != EXP_SIZES[i]) { code = 100.f + 4.f * (float)i; break; }
  }
  if (code == 0.f && out_size != 4063232) code = 400.f;
  if (code == 0.f && ws_size < (size_t)WS_NEEDED) code = 300.f;
  if (code != 0.f) {
    diag_kernel<<<1, 64, 0, stream>>>((float*)d_out, code);
    return;
  }

  // opt-in to >64KB dynamic LDS (host-side attribute; proven in R18/R19/R20)
  static int attr_done = 0;
  if (!attr_done) {
    attr_done = 1;
    (void)hipFuncSetAttribute((const void*)gru_main,
                              hipFuncAttributeMaxDynamicSharedMemorySize, LDS_DYN);
  }

  char* ws = (char*)d_ws;
  prep_kernel<<<512, 256, 0, stream>>>(
      (const float*)d_in[0], (const float*)d_in[1], (const float*)d_in[2],
      (const float*)d_in[3], (const float*)d_in[4], (const float*)d_in[5],
      (const float*)d_in[22], (const float*)d_in[23], (const float*)d_in[24], (const float*)d_in[25],
      ws);
  gru_main<<<NWG_TOTAL, 128, LDS_DYN, stream>>>(
      ws, (float*)d_out,
      (const float*)d_in[6], (const float*)d_in[7], (const float*)d_in[8], (const float*)d_in[9],
      (const float*)d_in[10], (const float*)d_in[11], (const float*)d_in[12], (const float*)d_in[13],
      (const float*)d_in[14], (const float*)d_in[15], (const float*)d_in[16], (const float*)d_in[17],
      (const float*)d_in[18], (const float*)d_in[19], (const float*)d_in[20], (const float*)d_in[21]);
}

// Round 11
// 8914.832 us; speedup vs baseline: 1.0098x; 1.0098x over previous
//
#include <hip/hip_runtime.h>

#define BDIM 128
#define TDIM 1024
#define HDIM 256
#define SLOT (BDIM*HDIM)
#define NWG_TOTAL 208             // 192 worker (3 layer x 4 rowgroup x 16 colslice) + 16 head
#define RING 14                   // h-plane ring depth per layer

// ws byte offsets. Flags: 16 groups x 16 x 32B = 8192 B.
#define FLAGS_OFF 0u              // u32 flag at idx (g*16+w)*8; g = l*4+rg (worker), 12+rg (head)
#define HD_OFF    8192u           // bf16 h digit planes [(l*RING+slot)*2+dig][B*H] = 5,505,024 B
#define XF_OFF    5513216u        // fp32 x features [B][T][6] = 3,145,728 B
#define DONEF_OFF 8658944u        // fp32 done [B][T] = 524,288 B
#define WS_NEEDED 9183232u        // <= proven 9,245,840
#define NZERO_U32 1378304         // (8192 + 5505024)/4

// dynamic LDS: worker = Wh frags [0,61440) + Wx frags [61440,122880); head 8KB
#define LDSW_BYTES 61440
#define LDS_DYN    122880

typedef __attribute__((ext_vector_type(8))) short bf16x8;
typedef __attribute__((ext_vector_type(4))) float f32x4;

static __device__ __forceinline__ unsigned short f2bf(float f) {
  union { float f; unsigned u; } v; v.f = f;
  unsigned r = v.u + 0x7fffu + ((v.u >> 16) & 1u);   // RNE
  return (unsigned short)(r >> 16);
}
static __device__ __forceinline__ float bf2f(unsigned short h) {
  union { unsigned u; float f; } v; v.u = ((unsigned)h) << 16;
  return v.f;
}
static __device__ __forceinline__ float sigm(float x) { return 1.f / (1.f + __expf(-x)); }
static __device__ __forceinline__ float tanha(float x) { return 1.f - 2.f / (1.f + __expf(2.f * x)); }

// data-plane coherence: relaxed agent atomics (LLC-routed) — R12-proven
static __device__ __forceinline__ unsigned long long ld_u64_coh(const void* p) {
  return __hip_atomic_load((const unsigned long long*)p, __ATOMIC_RELAXED, __HIP_MEMORY_SCOPE_AGENT);
}
static __device__ __forceinline__ void st_u32_coh(void* p, unsigned v) {
  __hip_atomic_store((unsigned*)p, v, __ATOMIC_RELAXED, __HIP_MEMORY_SCOPE_AGENT);
}

// coherent 16B load, NO wait — validity deferred to counted s_waitcnt vmcnt(N)
// + sched_barrier(0) (rule #18). sc0 sc1 = bypass L1 + per-XCD L2.
static __device__ __forceinline__ bf16x8 ld16_coh_nowait(const unsigned short* p) {
  bf16x8 v;
  asm volatile("global_load_dwordx4 %0, %1, off sc0 sc1" : "=v"(v) : "v"(p));
  return v;
}
template <int N>
static __device__ __forceinline__ void wait_vm() {
  asm volatile("s_waitcnt vmcnt(%0)" :: "i"(N) : "memory");
  __builtin_amdgcn_sched_barrier(0);
}

static __device__ __forceinline__ unsigned poll_flag(const unsigned* p) {
  return __hip_atomic_load(p, __ATOMIC_RELAXED, __HIP_MEMORY_SCOPE_AGENT);
}
static __device__ __forceinline__ void post_flag(unsigned* fl, int g, int w, int s1) {
  (void)__hip_atomic_exchange(fl + (g * 16 + w) * 8, (unsigned)s1,
                              __ATOMIC_RELAXED, __HIP_MEMORY_SCOPE_AGENT);
}

// blocking backpressure wait: lanes 0-15 check group g (four: only flags 0-3)
static __device__ __forceinline__ void bp_wait(unsigned* fl, int g, int tgt, bool four) {
  if (tgt <= 0) return;
  const int lane = threadIdx.x & 63;
  for (;;) {
    int ok = 1;
    if (lane < 16) {
      const int wi = four ? (lane & 3) : lane;
      ok = ((int)poll_flag(fl + (g * 16 + wi) * 8) >= tgt);
    }
    if (__all(ok)) break;
    __builtin_amdgcn_s_sleep(8);
  }
  asm volatile("" ::: "memory");
}

// one non-blocking poll round -> 64-bit readiness ballot.
// lanes 0-15: own-layer flag js=lane >= sOwn (own js auto-true);
// lanes 16-31: upstream flag js=lane-16 >= sUp (auto-true for L0); rest auto.
static __device__ __forceinline__ unsigned long long poll_round(
    unsigned* fl, int gOwn, int sOwn, int js, int gUp, int sUp, bool l0t) {
  const int lane = threadIdx.x & 63;
  int ok = 1;
  if (lane < 16) {
    if (lane != js && sOwn > 0)
      ok = ((int)poll_flag(fl + (gOwn * 16 + lane) * 8) >= sOwn);
  } else if (lane < 32 && !l0t) {
    ok = ((int)poll_flag(fl + (gUp * 16 + (lane - 16)) * 8) >= sUp);
  }
  return __ballot(ok);
}

// full-group wait (head path; R21-frozen)
static __device__ __forceinline__ void wave_wait2(unsigned* fl,
                                                  int g0, int t0, int skip0,
                                                  int g1, int t1,
                                                  int g2, int t2, bool g2four) {
  const int lane = threadIdx.x & 63;
  const int sel = lane >> 4;
  const int w = lane & 15;
  int g = g0, tgt = t0;
  if (sel == 1) { g = g1; tgt = t1; }
  if (sel == 2) { g = g2; tgt = t2; }
  if (sel == 3) tgt = 0;
  if (sel == 0 && w == skip0) tgt = 0;
  const int wi = (sel == 2 && g2four) ? (w & 3) : w;
  const unsigned* p = fl + (g * 16 + wi) * 8;
  const bool need = tgt > 0;
  for (;;) {
    int ok = 1;
    if (need) ok = ((int)poll_flag(p) >= tgt);
    if (__all(ok)) break;
    __builtin_amdgcn_s_sleep(8);
  }
  asm volatile("" ::: "memory");
}

__global__ void diag_kernel(float* out, float code) {
  if (threadIdx.x == 0 && blockIdx.x == 0) out[0] = code;
}

// ---------- prep: zero flags + h planes, build x-features, mirror done ----------
__global__ void prep_kernel(const float* __restrict__ rew, const float* __restrict__ done,
                            const float* __restrict__ gamma, const float* __restrict__ prob,
                            const float* __restrict__ y, const float* __restrict__ y1,
                            const float* __restrict__ w_e1, const float* __restrict__ b_e1,
                            const float* __restrict__ w_e2, const float* __restrict__ b_e2,
                            char* __restrict__ ws) {
  unsigned* zbase = (unsigned*)ws;
  float* donef = (float*)(ws + DONEF_OFF);
  float* xfeat = (float*)(ws + XF_OFF);

  __shared__ float we1[480], be1[16], we2[16];
  __shared__ float be2s, gam;
  for (int i = threadIdx.x; i < 480; i += blockDim.x) we1[i] = w_e1[i];
  if (threadIdx.x < 16) { be1[threadIdx.x] = b_e1[threadIdx.x]; we2[threadIdx.x] = w_e2[threadIdx.x]; }
  if (threadIdx.x == 0) { be2s = b_e2[0]; gam = gamma[0]; }
  __syncthreads();
  const int gid = blockIdx.x * blockDim.x + threadIdx.x;
  const int stride = gridDim.x * blockDim.x;

  for (int i = gid; i < NZERO_U32; i += stride) zbase[i] = 0u;
  for (int i = gid; i < BDIM * TDIM; i += stride) donef[i] = done[i];

  for (int i = gid; i < BDIM * TDIM; i += stride) {   // i = b*T + t
    float yr[30], y1r[30];
    #pragma unroll
    for (int c = 0; c < 30; ++c) { yr[c] = y[(size_t)i * 30 + c]; y1r[c] = y1[(size_t)i * 30 + c]; }
    float a0 = 0.f, a1 = 0.f;
    #pragma unroll 4
    for (int jm = 0; jm < 16; ++jm) {
      float s0 = be1[jm], s1 = be1[jm];
      #pragma unroll
      for (int c = 0; c < 30; ++c) { float w = we1[jm * 30 + c]; s0 += yr[c] * w; s1 += y1r[c] * w; }
      a0 += fmaxf(s0, 0.f) * we2[jm];
      a1 += fmaxf(s1, 0.f) * we2[jm];
    }
    float* xr = xfeat + (size_t)i * 6;
    xr[0] = rew[i]; xr[1] = done[i]; xr[2] = gam;
    xr[3] = prob[i]; xr[4] = sigm(a0 + be2s); xr[5] = sigm(a1 + be2s);
  }
}

// ---------------- worker WG: fine-grained per-pair chunk pipeline ----------------
// it-chunk reads cols it*32..+31 = siblings {2it,2it+1} (own layer, slot pp) and
// the same upstream pair (slot pc). Chunks processed in FIXED order 0..7 (per-
// accumulator MFMA order identical to R21 => bit-identical); loads 2-deep
// pipelined with counted vmcnt; laggard pairs only gate their own chunk.
template <bool L0T>
__device__ __forceinline__ void layer_body(int l, int rg, int js, char* __restrict__ ws,
                                           char* __restrict__ ldsW,
                                           char* __restrict__ ldsX,
                                           const float* __restrict__ Wh,
                                           const float* __restrict__ Wx,
                                           const float* __restrict__ bi,
                                           const float* __restrict__ bh,
                                           const float* __restrict__ wi0) {
  unsigned short* hd = (unsigned short*)(ws + HD_OFF);
  unsigned* fl = (unsigned*)(ws + FLAGS_OFF);
  const float* donef = (const float*)(ws + DONEF_OFF);
  const float* xfeat = (const float*)(ws + XF_OFF);

  const int tid = threadIdx.x;
  const int wv = tid >> 6, lane = tid & 63, q = lane >> 4, jj = lane & 15;
  const int j = js * 16 + jj;

  const float bi_r = bi[j], bi_z = bi[256 + j], bi_n = bi[512 + j];
  const float bh_r = bh[j], bh_z = bh[256 + j], bh_n = bh[512 + j];

  // stage Wh digit frags -> LDS (128 threads; R18-proven layout)
  for (int idx = tid; idx < 12288; idx += 128) {
    const int row = idx >> 8, k = idx & 255;
    const int g = row >> 4, jr = row & 15;
    const float w = Wh[(size_t)(g * 256 + js * 16 + jr) * 256 + k];
    const unsigned short d1 = f2bf(w);
    const unsigned short d2 = f2bf(w - bf2f(d1));
    const int itc = k >> 5, kk = k & 31;
    *(unsigned short*)(ldsW + ((g * 2 + 0) * 8 + itc) * 1280 + jr * 80 + kk * 2) = d1;
    *(unsigned short*)(ldsW + ((g * 2 + 1) * 8 + itc) * 1280 + jr * 80 + kk * 2) = d2;
  }
  if (!L0T) {
    for (int idx = tid; idx < 12288; idx += 128) {
      const int row = idx >> 8, k = idx & 255;
      const int g = row >> 4, jr = row & 15;
      const float w = Wx[(size_t)(g * 256 + js * 16 + jr) * 256 + k];
      const unsigned short d1 = f2bf(w);
      const unsigned short d2 = f2bf(w - bf2f(d1));
      const int itc = k >> 5, kk = k & 31;
      *(unsigned short*)(ldsX + ((g * 2 + 0) * 8 + itc) * 1280 + jr * 80 + kk * 2) = d1;
      *(unsigned short*)(ldsX + ((g * 2 + 1) * 8 + itc) * 1280 + jr * 80 + kk * 2) = d2;
    }
  }
  __syncthreads();

  float wx0[3][6];
  if (L0T) {
    #pragma unroll
    for (int g = 0; g < 3; ++g)
      #pragma unroll
      for (int c = 0; c < 6; ++c) wx0[g][c] = wi0[(g * 256 + j) * 6 + c];
  }

  float hc[4];                     // fp32 carry: this wave's 16 rows x 16 cols
  #pragma unroll
  for (int i = 0; i < 4; ++i) hc[i] = 0.f;

  const int mA = (rg * 2 + wv) * 16 + jj;   // this wave's A-row base
  const f32x4 z4 = {0.f, 0.f, 0.f, 0.f};
  const int gOwn = l * 4 + rg;
  const int gUp  = L0T ? 0 : (l - 1) * 4 + rg;
  const int gDn  = (l == 2) ? (12 + rg) : (l + 1) * 4 + rg;
  const bool dn4 = (l == 2);

  for (int s = 0; s < 1024; ++s) {
    const int t = 1023 - s;
    const int pc = s % RING, pp = (s + RING - 1) % RING;

    // prefetch done factors (drained by the compiler's poll waits)
    float sFv[4];
    #pragma unroll
    for (int i = 0; i < 4; ++i)
      sFv[i] = 1.f - donef[((rg * 2 + wv) * 16 + q * 4 + i) * TDIM + t];

    // backpressure (deep ring), then one readiness poll round
    bp_wait(fl, gDn, s - (RING - 1), dn4);
    unsigned long long M = poll_round(fl, gOwn, s, js, gUp, s + 1, L0T);

    const unsigned short* hh1 = hd + (size_t)((l * RING + pp) * 2 + 0) * SLOT;
    const unsigned short* hh2 = hd + (size_t)((l * RING + pp) * 2 + 1) * SLOT;
    const unsigned short* hx1 = L0T ? (const unsigned short*)0 : hd + (size_t)(((l - 1) * RING + pc) * 2 + 0) * SLOT;
    const unsigned short* hx2 = L0T ? (const unsigned short*)0 : hd + (size_t)(((l - 1) * RING + pc) * 2 + 1) * SLOT;
    unsigned short* hdw1 = hd + (size_t)((l * RING + pc) * 2 + 0) * SLOT;
    unsigned short* hdw2 = hd + (size_t)((l * RING + pc) * 2 + 1) * SLOT;

    f32x4 Ch[3], Cx[3];
    #pragma unroll
    for (int g = 0; g < 3; ++g) { Ch[g] = z4; Cx[g] = z4; }

    bf16x8 A1[8], A2[8], X1[8], X2[8];
    unsigned ism = 0;   // issued-chunk bitmask (wave-uniform)

    auto canp = [&](int p) -> bool {
      const unsigned own = (unsigned)((M >> (2 * p)) & 3ull);
      const unsigned up  = (unsigned)((M >> (16 + 2 * p)) & 3ull);
      return own == 3u && up == 3u;
    };

    #pragma unroll
    for (int it = 0; it < 8; ++it) {
      // blocking: ensure chunk it issued (in order)
      if (!((ism >> it) & 1u)) {
        while (!canp(it)) {
          __builtin_amdgcn_s_sleep(1);
          M = poll_round(fl, gOwn, s, js, gUp, s + 1, L0T);
        }
        {
          const size_t ro = (size_t)mA * 256 + it * 32 + q * 8;
          A1[it] = ld16_coh_nowait(hh1 + ro);
          A2[it] = ld16_coh_nowait(hh2 + ro);
          if constexpr (!L0T) { X1[it] = ld16_coh_nowait(hx1 + ro); X2[it] = ld16_coh_nowait(hx2 + ro); }
        }
        ism |= 1u << it;
      }
      // counted wait: younger chunks in flight = {0,1,2}
      {
        const int y = ((it + 1 < 8) ? (int)((ism >> (it + 1)) & 1u) : 0)
                    + ((it + 2 < 8) ? (int)((ism >> (it + 2)) & 1u) : 0);
        if (y == 0) wait_vm<0>();
        else if (y == 1) { if constexpr (L0T) wait_vm<2>(); else wait_vm<4>(); }
        else             { if constexpr (L0T) wait_vm<4>(); else wait_vm<8>(); }
      }
      // compute chunk it (per-accumulator order identical to R21)
      {
        const int cb = it * 1280 + jj * 80 + q * 16;
        #pragma unroll
        for (int g = 0; g < 3; ++g) {
          #pragma unroll
          for (int dig = 0; dig < 2; ++dig) {
            const bf16x8 wb = *(const bf16x8*)(ldsW + ((g * 2 + dig) * 8) * 1280 + cb);
            Ch[g] = __builtin_amdgcn_mfma_f32_16x16x32_bf16(A1[it], wb, Ch[g], 0, 0, 0);
            Ch[g] = __builtin_amdgcn_mfma_f32_16x16x32_bf16(A2[it], wb, Ch[g], 0, 0, 0);
          }
        }
        if constexpr (!L0T) {
          #pragma unroll
          for (int g = 0; g < 3; ++g) {
            #pragma unroll
            for (int dig = 0; dig < 2; ++dig) {
              const bf16x8 xb = *(const bf16x8*)(ldsX + ((g * 2 + dig) * 8) * 1280 + cb);
              Cx[g] = __builtin_amdgcn_mfma_f32_16x16x32_bf16(X1[it], xb, Cx[g], 0, 0, 0);
              Cx[g] = __builtin_amdgcn_mfma_f32_16x16x32_bf16(X2[it], xb, Cx[g], 0, 0, 0);
            }
          }
        }
      }
      // nonblocking prefetch (strict chunk order; depth <= 2)
      if (it + 1 < 8 && !((ism >> (it + 1)) & 1u) && canp(it + 1)) {
        const int c1 = it + 1;
        const size_t ro = (size_t)mA * 256 + c1 * 32 + q * 8;
        A1[c1] = ld16_coh_nowait(hh1 + ro);
        A2[c1] = ld16_coh_nowait(hh2 + ro);
        if constexpr (!L0T) { X1[c1] = ld16_coh_nowait(hx1 + ro); X2[c1] = ld16_coh_nowait(hx2 + ro); }
        ism |= 1u << c1;
      }
      if (it + 2 < 8 && ((ism >> (it + 1)) & 1u) && !((ism >> (it + 2)) & 1u) && canp(it + 2)) {
        const int c2 = it + 2;
        const size_t ro = (size_t)mA * 256 + c2 * 32 + q * 8;
        A1[c2] = ld16_coh_nowait(hh1 + ro);
        A2[c2] = ld16_coh_nowait(hh2 + ro);
        if constexpr (!L0T) { X1[c2] = ld16_coh_nowait(hx1 + ro); X2[c2] = ld16_coh_nowait(hx2 + ro); }
        ism |= 1u << c2;
      }
    }

    // epilogue (verified; C/D layout row=q*4+i, col=jj)
    #pragma unroll
    for (int i = 0; i < 4; ++i) {
      const int mC = (rg * 2 + wv) * 16 + q * 4 + i;
      const float sF = sFv[i];
      float gxr, gxz, gxn;
      if (L0T) {
        const float* xr = xfeat + ((size_t)mC * TDIM + t) * 6;
        gxr = 0.f; gxz = 0.f; gxn = 0.f;
        #pragma unroll
        for (int c = 0; c < 6; ++c) {
          const float xv = xr[c];
          gxr += xv * wx0[0][c]; gxz += xv * wx0[1][c]; gxn += xv * wx0[2][c];
        }
      } else {
        gxr = Cx[0][i]; gxz = Cx[1][i]; gxn = Cx[2][i];
      }
      const float r = sigm(gxr + bi_r + sF * Ch[0][i] + bh_r);
      const float z = sigm(gxz + bi_z + sF * Ch[1][i] + bh_z);
      const float n = tanha(gxn + bi_n + r * (sF * Ch[2][i] + bh_n));
      const float hp = hc[i] * sF;
      const float hv = (1.f - z) * n + z * hp;
      hc[i] = hv;
      // lane-pair pack: even jj stores d1-plane u32 pair, odd jj d2-plane
      const unsigned short d1 = f2bf(hv);
      const unsigned short d2 = f2bf(hv - bf2f(d1));
      const int o1 = __shfl_xor((int)d1, 1, 64);
      const int o2 = __shfl_xor((int)d2, 1, 64);
      const unsigned val = (jj & 1) ? ((unsigned)(o2 & 0xffff) | ((unsigned)d2 << 16))
                                    : ((unsigned)d1 | ((unsigned)(o1 & 0xffff) << 16));
      unsigned short* bp = ((jj & 1) ? hdw2 : hdw1) + (size_t)mC * 256 + (j & ~1);
      st_u32_coh(bp, val);
    }

    // drain this wave's stores, join sibling wave, then flag post (RMW)
    asm volatile("s_waitcnt vmcnt(0)" ::: "memory");
    __syncthreads();
    if (tid == 0) post_flag(fl, gOwn, js, s + 1);
  }
}

// ---------------- head WG (128 threads, 8 batch rows) — R21-frozen ----------------
__device__ __forceinline__ void head_body(int hw, char* __restrict__ ws, float* __restrict__ out,
                                          char* __restrict__ lds,
                                          const float* __restrict__ wfy,
                                          const float* __restrict__ bfy,
                                          const float* __restrict__ wfp,
                                          const float* __restrict__ bfp) {
  const unsigned short* hd = (const unsigned short*)(ws + HD_OFF);
  unsigned* fl = (unsigned*)(ws + FLAGS_OFF);
  float* hlds = (float*)lds;        // 8 rows x 256 f32 = 8KB

  const int tid = threadIdx.x;
  const int rg = hw >> 2;

  for (int s = 0; s < 1024; ++s) {
    const int t = 1023 - s;
    const int pc = s % RING;
    wave_wait2(fl, 8 + rg, s + 1, -1, 0, 0, 0, 0, false);

    // stage 8 rows: reconstruct h = d1 + d2 into LDS (2 x 128-lane passes)
    #pragma unroll
    for (int sub = 0; sub < 2; ++sub) {
      const int te = tid + 128 * sub;
      const size_t rowoff = (size_t)(hw * 8 + (te >> 5)) * 256 + (te & 31) * 8;
      const unsigned short* p1 = hd + (size_t)((2 * RING + pc) * 2 + 0) * SLOT + rowoff;
      const unsigned short* p2 = hd + (size_t)((2 * RING + pc) * 2 + 1) * SLOT + rowoff;
      unsigned long long q10 = ld_u64_coh(p1);
      unsigned long long q11 = ld_u64_coh(p1 + 4);
      unsigned long long q20 = ld_u64_coh(p2);
      unsigned long long q21 = ld_u64_coh(p2 + 4);
      float* dst = hlds + (te >> 5) * 256 + (te & 31) * 8;
      #pragma unroll
      for (int e = 0; e < 4; ++e) {
        dst[e]     = bf2f((unsigned short)(q10 >> (16 * e))) + bf2f((unsigned short)(q20 >> (16 * e)));
        dst[4 + e] = bf2f((unsigned short)(q11 >> (16 * e))) + bf2f((unsigned short)(q21 >> (16 * e)));
      }
    }
    __syncthreads();
    #pragma unroll
    for (int sub = 0; sub < 2; ++sub) {
      const int te = tid + 128 * sub;
      const int d = te & 31;
      const int bb = te >> 5;
      const int b = hw * 8 + bb;
      if (d < 31) {
        const float* wrow = (d < 30) ? (wfy + d * 256) : wfp;
        const float biasv = (d < 30) ? bfy[d] : bfp[0];
        const float* hr = hlds + bb * 256;
        float a0 = 0.f, a1 = 0.f;
        #pragma unroll 8
        for (int kk = 0; kk < 256; kk += 8) {
          const f32x4 h0 = *(const f32x4*)(hr + kk);
          const f32x4 h1 = *(const f32x4*)(hr + kk + 4);
          const f32x4 w0 = *(const f32x4*)(wrow + kk);
          const f32x4 w1 = *(const f32x4*)(wrow + kk + 4);
          a0 += h0[0]*w0[0] + h0[1]*w0[1] + h0[2]*w0[2] + h0[3]*w0[3];
          a1 += h1[0]*w1[0] + h1[1]*w1[1] + h1[2]*w1[2] + h1[3]*w1[3];
        }
        const float acc = a0 + a1;
        if (d < 30) out[BDIM * TDIM + ((size_t)b * TDIM + t) * 30 + d] = sigm(acc + biasv);
        else        out[(size_t)b * TDIM + t] = acc + biasv;
      }
    }
    __syncthreads();
    if (tid == 0) post_flag(fl, 12 + rg, hw & 3, s + 1);
  }
}

__global__ void __launch_bounds__(128, 1) gru_main(char* __restrict__ ws,
                                                   float* __restrict__ out,
                                                   const float* __restrict__ wi0,
                                                   const float* __restrict__ wh0,
                                                   const float* __restrict__ bi0,
                                                   const float* __restrict__ bh0,
                                                   const float* __restrict__ wi1,
                                                   const float* __restrict__ wh1,
                                                   const float* __restrict__ bi1,
                                                   const float* __restrict__ bh1,
                                                   const float* __restrict__ wi2,
                                                   const float* __restrict__ wh2,
                                                   const float* __restrict__ bi2,
                                                   const float* __restrict__ bh2,
                                                   const float* __restrict__ wfy,
                                                   const float* __restrict__ bfy,
                                                   const float* __restrict__ wfp,
                                                   const float* __restrict__ bfp) {
  extern __shared__ char lds[];
  const int bid = blockIdx.x;
  if (bid < 192) {
    const int l = bid >> 6;
    const int rg = (bid >> 4) & 3;
    const int js = bid & 15;
    const float* Wh = (l == 0) ? wh0 : (l == 1) ? wh1 : wh2;
    const float* Wx = (l == 0) ? (const float*)0 : (l == 1) ? wi1 : wi2;
    const float* bi = (l == 0) ? bi0 : (l == 1) ? bi1 : bi2;
    const float* bh = (l == 0) ? bh0 : (l == 1) ? bh1 : bh2;
    if (l == 0) layer_body<true>(l, rg, js, ws, lds, lds + LDSW_BYTES, Wh, Wx, bi, bh, wi0);
    else        layer_body<false>(l, rg, js, ws, lds, lds + LDSW_BYTES, Wh, Wx, bi, bh, wi0);
  } else {
    head_body(bid - 192, ws, out, lds, wfy, bfy, wfp, bfp);
  }
}

extern "C" void kernel_launch(void* const* d_in, const int* in_sizes, int n_in,
                              void* d_out, int out_size, void* d_ws, size_t ws_size,
                              hipStream_t stream) {
  static const int EXP_SIZES[26] = {131072, 131072, 1, 131072, 3932160, 3932160,
                                    4608, 196608, 768, 768,
                                    196608, 196608, 768, 768,
                                    196608, 196608, 768, 768,
                                    7680, 30, 256, 1, 480, 16, 16, 1};
  float code = 0.f;
  if (n_in != 26) code = 900.f;
  if (code == 0.f) {
    for (int i = 0; i < 26; ++i)
      if (in_sizes[i] != EXP_SIZES[i]) { code = 100.f + 4.f * (float)i; break; }
  }
  if (code == 0.f && out_size != 4063232) code = 400.f;
  if (code == 0.f && ws_size < (size_t)WS_NEEDED) code = 300.f;
  if (code != 0.f) {
    diag_kernel<<<1, 64, 0, stream>>>((float*)d_out, code);
    return;
  }

  // opt-in to >64KB dynamic LDS (host-side attribute; proven in R18-R21)
  static int attr_done = 0;
  if (!attr_done) {
    attr_done = 1;
    (void)hipFuncSetAttribute((const void*)gru_main,
                              hipFuncAttributeMaxDynamicSharedMemorySize, LDS_DYN);
  }

  char* ws = (char*)d_ws;
  prep_kernel<<<512, 256, 0, stream>>>(
      (const float*)d_in[0], (const float*)d_in[1], (const float*)d_in[2],
      (const float*)d_in[3], (const float*)d_in[4], (const float*)d_in[5],
      (const float*)d_in[22], (const float*)d_in[23], (const float*)d_in[24], (const float*)d_in[25],
      ws);
  gru_main<<<NWG_TOTAL, 128, LDS_DYN, stream>>>(
      ws, (float*)d_out,
      (const float*)d_in[6], (const float*)d_in[7], (const float*)d_in[8], (const float*)d_in[9],
      (const float*)d_in[10], (const float*)d_in[11], (const float*)d_in[12], (const float*)d_in[13],
      (const float*)d_in[14], (const float*)d_in[15], (const float*)d_in[16], (const float*)d_in[17],
      (const float*)d_in[18], (const float*)d_in[19], (const float*)d_in[20], (const float*)d_in[21]);
}